// Round 2
// baseline (1884.773 us; speedup 1.0000x reference)
//
#include <hip/hip_runtime.h>
#include <hip/hip_bf16.h>

typedef __attribute__((ext_vector_type(4))) float f32x4;
typedef __attribute__((ext_vector_type(8))) short bf16x8;
typedef unsigned int   u32;
typedef unsigned short u16;

#define D_DIM 2048
#define I_DIM 768
#define NE    64
#define CAP   1024
#define NTOK  4096

__device__ __forceinline__ u32 cvt2(float a, float b) {
  __hip_bfloat162 hh = __float22bfloat162_rn(float2{a, b});
  union { __hip_bfloat162 h; u32 u; } c; c.h = hh; return c.u;
}
__device__ __forceinline__ u16 f2b(float f) {
  __hip_bfloat16 b = __float2bfloat16(f);
  union { __hip_bfloat16 b; u16 u; } c; c.b = b; return c.u;
}
// async global->LDS, 16B per lane. LDS dest = wave-uniform base + lane*16.
__device__ __forceinline__ void glp16(const void* g, void* l) {
  __builtin_amdgcn_global_load_lds(
      (const __attribute__((address_space(1))) u32*)g,
      (__attribute__((address_space(3))) u32*)l, 16, 0, 0);
}

// ---------------- x fp32 -> bf16 ----------------
__global__ __launch_bounds__(256) void k_cvt_x(const float* __restrict__ x,
                                               u16* __restrict__ xb) {
  const size_t i = ((size_t)blockIdx.x * 256 + threadIdx.x) * 8;
  float4 v0 = *(const float4*)(x + i);
  float4 v1 = *(const float4*)(x + i + 4);
  uint4 o;
  o.x = cvt2(v0.x, v0.y); o.y = cvt2(v0.z, v0.w);
  o.z = cvt2(v1.x, v1.y); o.w = cvt2(v1.z, v1.w);
  *(uint4*)(xb + i) = o;
}

// ---------------- router: fp32 logits, top-8, renorm, dispatch ----------------
__global__ __launch_bounds__(256) void k_router(
    const float* __restrict__ x, const float* __restrict__ rw,
    int* __restrict__ counts, int* __restrict__ slot_token,
    float* __restrict__ slot_w)
{
  const int lane = threadIdx.x & 63;
  const int tok  = blockIdx.x * 4 + (threadIdx.x >> 6);
  const float* xr = x + (size_t)tok * D_DIM;

  float acc = 0.f;
  for (int d0 = 0; d0 < D_DIM; d0 += 64) {
    float xv = xr[d0 + lane];
    #pragma unroll
    for (int j = 0; j < 64; ++j) {
      float xj = __shfl(xv, j, 64);
      acc = fmaf(xj, rw[(size_t)(d0 + j) * NE + lane], acc);
    }
  }

  float v = acc; int vi = lane;
  float wk[8]; int ei[8];
  float mx0 = 0.f, wsum = 0.f;
  #pragma unroll
  for (int k = 0; k < 8; ++k) {
    float mv = v; int mi = vi;
    #pragma unroll
    for (int off = 32; off >= 1; off >>= 1) {
      float ov = __shfl_xor(mv, off, 64);
      int   oi = __shfl_xor(mi, off, 64);
      if (ov > mv || (ov == mv && oi < mi)) { mv = ov; mi = oi; }
    }
    if (k == 0) mx0 = mv;
    float ew = __expf(mv - mx0);
    wk[k] = ew; ei[k] = mi; wsum += ew;
    if (lane == mi) v = -3.4e38f;
  }

  if (lane == 0) {
    float inv = 1.f / wsum;
    #pragma unroll
    for (int k = 0; k < 8; ++k) {
      int ee   = ei[k];
      int slot = atomicAdd(&counts[ee], 1);
      if (slot < CAP) {
        slot_token[ee * CAP + slot] = tok;
        slot_w[ee * CAP + slot]     = wk[k] * inv;
      }
    }
  }
}

// ---------------- gate/up fused GEMM + SwiGLU -> h (bf16) ----------------
// grid (mt=8, nt=12, e=64), block 256. Tile 128m x 64n, BK=64.
// LDS layout: cells of 8 contiguous k (16B): As[kg][m][8], B*[kg][n][8].
__global__ __launch_bounds__(256) void k_mlp1(
    const u16* __restrict__ xb, const float* __restrict__ gate,
    const float* __restrict__ up, const int* __restrict__ counts,
    const int* __restrict__ slot_token, u16* __restrict__ h)
{
  const int e = blockIdx.z, mt = blockIdx.x, nt = blockIdx.y;
  int cnt = counts[e]; if (cnt > CAP) cnt = CAP;
  const int m0 = mt * 128;
  if (m0 >= cnt) return;
  const int n0 = nt * 64;

  const int t = threadIdx.x;
  const int lane = t & 63, wv = t >> 6;
  const int li = lane & 15, gq = lane >> 4;
  const int wr = wv >> 1, wc = wv & 1;

  __shared__ u16 As[8 * 128 * 8];   // 16 KB
  __shared__ u16 Bg[8 * 64 * 8];    //  8 KB
  __shared__ u16 Bu[8 * 64 * 8];    //  8 KB

  // A gather setup: wave stages m-half mh, kg range kgA..kgA+3
  const int mh  = wv & 1;
  const int kgA = (wv >> 1) * 4;
  const int tok = slot_token[e * CAP + m0 + mh * 64 + lane];  // dead slots -> 0
  const u16* xrow = xb + (size_t)tok * D_DIM;

  // B convert-transpose: thread owns cells (kg = 2*wv+c, n = lane)
  const float* gb = gate + (size_t)e * D_DIM * I_DIM + n0 + lane;
  const float* ub = up   + (size_t)e * D_DIM * I_DIM + n0 + lane;

  f32x4 ag[4][2], au[4][2];
  #pragma unroll
  for (int m = 0; m < 4; ++m)
    #pragma unroll
    for (int n = 0; n < 2; ++n) {
      f32x4 z = {0.f, 0.f, 0.f, 0.f};
      ag[m][n] = z; au[m][n] = z;
    }

  for (int kk = 0; kk < D_DIM; kk += 64) {
    // A: 4 async 16B/lane copies (bf16, no VALU)
    #pragma unroll
    for (int i = 0; i < 4; ++i) {
      const int kg = kgA + i;
      glp16(xrow + kk + kg * 8, &As[(kg * 128 + mh * 64) * 8]);
    }
    // B: coalesced fp32 rows -> cvt_pk -> conflict-free b128 writes
    #pragma unroll
    for (int c = 0; c < 2; ++c) {
      const int kg = wv * 2 + c;
      const float* gp = gb + (size_t)(kk + kg * 8) * I_DIM;
      const float* pp = ub + (size_t)(kk + kg * 8) * I_DIM;
      float gv[8], uv[8];
      #pragma unroll
      for (int j = 0; j < 8; ++j) {
        gv[j] = gp[(size_t)j * I_DIM];
        uv[j] = pp[(size_t)j * I_DIM];
      }
      uint4 og, ou;
      og.x = cvt2(gv[0], gv[1]); og.y = cvt2(gv[2], gv[3]);
      og.z = cvt2(gv[4], gv[5]); og.w = cvt2(gv[6], gv[7]);
      ou.x = cvt2(uv[0], uv[1]); ou.y = cvt2(uv[2], uv[3]);
      ou.z = cvt2(uv[4], uv[5]); ou.w = cvt2(uv[6], uv[7]);
      *(uint4*)&Bg[(kg * 64 + lane) * 8] = og;
      *(uint4*)&Bu[(kg * 64 + lane) * 8] = ou;
    }
    __syncthreads();

    #pragma unroll
    for (int kc = 0; kc < 2; ++kc) {
      const int kg = kc * 4 + gq;
      bf16x8 a0 = *(const bf16x8*)&As[(kg * 128 + wr * 64 +      li) * 8];
      bf16x8 a1 = *(const bf16x8*)&As[(kg * 128 + wr * 64 + 16 + li) * 8];
      bf16x8 a2 = *(const bf16x8*)&As[(kg * 128 + wr * 64 + 32 + li) * 8];
      bf16x8 a3 = *(const bf16x8*)&As[(kg * 128 + wr * 64 + 48 + li) * 8];
      bf16x8 g0 = *(const bf16x8*)&Bg[(kg * 64 + wc * 32 +      li) * 8];
      bf16x8 g1 = *(const bf16x8*)&Bg[(kg * 64 + wc * 32 + 16 + li) * 8];
      bf16x8 u0 = *(const bf16x8*)&Bu[(kg * 64 + wc * 32 +      li) * 8];
      bf16x8 u1 = *(const bf16x8*)&Bu[(kg * 64 + wc * 32 + 16 + li) * 8];
      ag[0][0] = __builtin_amdgcn_mfma_f32_16x16x32_bf16(a0, g0, ag[0][0], 0, 0, 0);
      ag[1][0] = __builtin_amdgcn_mfma_f32_16x16x32_bf16(a1, g0, ag[1][0], 0, 0, 0);
      ag[2][0] = __builtin_amdgcn_mfma_f32_16x16x32_bf16(a2, g0, ag[2][0], 0, 0, 0);
      ag[3][0] = __builtin_amdgcn_mfma_f32_16x16x32_bf16(a3, g0, ag[3][0], 0, 0, 0);
      ag[0][1] = __builtin_amdgcn_mfma_f32_16x16x32_bf16(a0, g1, ag[0][1], 0, 0, 0);
      ag[1][1] = __builtin_amdgcn_mfma_f32_16x16x32_bf16(a1, g1, ag[1][1], 0, 0, 0);
      ag[2][1] = __builtin_amdgcn_mfma_f32_16x16x32_bf16(a2, g1, ag[2][1], 0, 0, 0);
      ag[3][1] = __builtin_amdgcn_mfma_f32_16x16x32_bf16(a3, g1, ag[3][1], 0, 0, 0);
      au[0][0] = __builtin_amdgcn_mfma_f32_16x16x32_bf16(a0, u0, au[0][0], 0, 0, 0);
      au[1][0] = __builtin_amdgcn_mfma_f32_16x16x32_bf16(a1, u0, au[1][0], 0, 0, 0);
      au[2][0] = __builtin_amdgcn_mfma_f32_16x16x32_bf16(a2, u0, au[2][0], 0, 0, 0);
      au[3][0] = __builtin_amdgcn_mfma_f32_16x16x32_bf16(a3, u0, au[3][0], 0, 0, 0);
      au[0][1] = __builtin_amdgcn_mfma_f32_16x16x32_bf16(a0, u1, au[0][1], 0, 0, 0);
      au[1][1] = __builtin_amdgcn_mfma_f32_16x16x32_bf16(a1, u1, au[1][1], 0, 0, 0);
      au[2][1] = __builtin_amdgcn_mfma_f32_16x16x32_bf16(a2, u1, au[2][1], 0, 0, 0);
      au[3][1] = __builtin_amdgcn_mfma_f32_16x16x32_bf16(a3, u1, au[3][1], 0, 0, 0);
    }
    __syncthreads();
  }

  // epilogue: h = silu(g) * u, bf16. Write all 128 rows (dead rows harmless).
  #pragma unroll
  for (int mf = 0; mf < 4; ++mf) {
    #pragma unroll
    for (int j = 0; j < 4; ++j) {
      const int slot = m0 + wr * 64 + mf * 16 + gq * 4 + j;
      u16* hr = h + (size_t)(e * CAP + slot) * I_DIM + n0 + wc * 32 + li;
      #pragma unroll
      for (int nf = 0; nf < 2; ++nf) {
        float gg = ag[mf][nf][j];
        float uu = au[mf][nf][j];
        hr[nf * 16] = f2b(gg * uu / (1.f + __expf(-gg)));
      }
    }
  }
}

// ---------------- down GEMM + weighted scatter-add ----------------
// grid (mt=8, nt=16, e=64), block 256. Tile 128m x 128n, BK=64.
__global__ __launch_bounds__(256) void k_mlp2(
    const u16* __restrict__ h, const float* __restrict__ down,
    const int* __restrict__ counts, const int* __restrict__ slot_token,
    const float* __restrict__ slot_w, float* __restrict__ out)
{
  const int e = blockIdx.z, mt = blockIdx.x, nt = blockIdx.y;
  int cnt = counts[e]; if (cnt > CAP) cnt = CAP;
  const int m0 = mt * 128;
  if (m0 >= cnt) return;
  const int n0 = nt * 128;

  const int t = threadIdx.x;
  const int lane = t & 63, wv = t >> 6;
  const int li = lane & 15, gq = lane >> 4;
  const int wm = (wv >> 1) * 64, wn = (wv & 1) * 64;

  __shared__ u16 As[8 * 128 * 8];   // [kg][m][8]  16 KB
  __shared__ u16 Bt[8 * 128 * 8];   // [kg][n][8]  16 KB

  const int mh  = wv & 1;
  const int kgA = (wv >> 1) * 4;
  const u16* hrow = h + (size_t)(e * CAP + m0 + mh * 64 + lane) * I_DIM;

  const int nh  = wv >> 1;
  const int kgB = (wv & 1) * 4;
  const float* db = down + (size_t)e * I_DIM * D_DIM + n0 + nh * 64 + lane;

  f32x4 acc[4][4];
  #pragma unroll
  for (int m = 0; m < 4; ++m)
    #pragma unroll
    for (int n = 0; n < 4; ++n) { f32x4 z = {0.f,0.f,0.f,0.f}; acc[m][n] = z; }

  for (int kk = 0; kk < I_DIM; kk += 64) {
    #pragma unroll
    for (int i = 0; i < 4; ++i) {
      const int kg = kgA + i;
      glp16(hrow + kk + kg * 8, &As[(kg * 128 + mh * 64) * 8]);
    }
    #pragma unroll
    for (int c = 0; c < 4; ++c) {
      const int kg = kgB + c;
      const float* dp = db + (size_t)(kk + kg * 8) * D_DIM;
      float v[8];
      #pragma unroll
      for (int j = 0; j < 8; ++j) v[j] = dp[(size_t)j * D_DIM];
      uint4 o;
      o.x = cvt2(v[0], v[1]); o.y = cvt2(v[2], v[3]);
      o.z = cvt2(v[4], v[5]); o.w = cvt2(v[6], v[7]);
      *(uint4*)&Bt[(kg * 128 + nh * 64 + lane) * 8] = o;
    }
    __syncthreads();

    #pragma unroll
    for (int kc = 0; kc < 2; ++kc) {
      const int kg = kc * 4 + gq;
      bf16x8 a[4], b[4];
      #pragma unroll
      for (int mf = 0; mf < 4; ++mf)
        a[mf] = *(const bf16x8*)&As[(kg * 128 + wm + mf * 16 + li) * 8];
      #pragma unroll
      for (int nf = 0; nf < 4; ++nf)
        b[nf] = *(const bf16x8*)&Bt[(kg * 128 + wn + nf * 16 + li) * 8];
      #pragma unroll
      for (int mf = 0; mf < 4; ++mf)
        #pragma unroll
        for (int nf = 0; nf < 4; ++nf)
          acc[mf][nf] = __builtin_amdgcn_mfma_f32_16x16x32_bf16(a[mf], b[nf], acc[mf][nf], 0, 0, 0);
    }
    __syncthreads();
  }

  #pragma unroll
  for (int mf = 0; mf < 4; ++mf) {
    #pragma unroll
    for (int j = 0; j < 4; ++j) {
      const int slot = m0 + wm + mf * 16 + gq * 4 + j;
      if (slot < cnt) {
        const int   tk  = slot_token[e * CAP + slot];
        const float wgt = slot_w[e * CAP + slot];
        float* orow = out + (size_t)tk * D_DIM + n0 + wn + li;
        #pragma unroll
        for (int nf = 0; nf < 4; ++nf)
          atomicAdd(&orow[nf * 16], wgt * acc[mf][nf][j]);
      }
    }
  }
}

extern "C" void kernel_launch(void* const* d_in, const int* in_sizes, int n_in,
                              void* d_out, int out_size, void* d_ws, size_t ws_size,
                              hipStream_t stream) {
  const float* x    = (const float*)d_in[0];
  const float* rw   = (const float*)d_in[1];
  const float* gate = (const float*)d_in[2];
  const float* up   = (const float*)d_in[3];
  const float* down = (const float*)d_in[4];
  float* out = (float*)d_out;

  char* ws = (char*)d_ws;
  int*   counts     = (int*)ws;                                    // 256 B (pad 1 KB)
  int*   slot_token = (int*)(ws + 1024);                           // 256 KB
  float* slot_w     = (float*)(ws + 1024 + (size_t)NE * CAP * 4);  // 256 KB
  u16*   xb         = (u16*)(ws + 1024 + (size_t)NE * CAP * 8);    // 16.78 MB
  u16*   h          = (u16*)(ws + 1024 + (size_t)NE * CAP * 8
                                  + (size_t)NTOK * D_DIM * 2);     // 100.7 MB

  hipMemsetAsync(counts, 0, NE * sizeof(int), stream);
  hipMemsetAsync(slot_token, 0, (size_t)NE * CAP * sizeof(int), stream);
  hipMemsetAsync(out, 0, (size_t)out_size * sizeof(float), stream);

  k_cvt_x <<<dim3((NTOK * D_DIM) / (256 * 8)), 256, 0, stream>>>(x, xb);
  k_router<<<dim3(NTOK / 4),                   256, 0, stream>>>(x, rw, counts, slot_token, slot_w);
  k_mlp1  <<<dim3(8, 12, NE),                  256, 0, stream>>>(xb, gate, up, counts, slot_token, h);
  k_mlp2  <<<dim3(8, 16, NE),                  256, 0, stream>>>(h, down, counts, slot_token, slot_w, out);
}

// Round 3
// 1425.718 us; speedup vs baseline: 1.3220x; 1.3220x over previous
//
#include <hip/hip_runtime.h>
#include <hip/hip_bf16.h>

typedef __attribute__((ext_vector_type(4))) float f32x4;
typedef __attribute__((ext_vector_type(8))) short bf16x8;
typedef unsigned int   u32;
typedef unsigned short u16;

#define D_DIM 2048
#define I_DIM 768
#define NE    64
#define CAP   1024
#define NTOK  4096

__device__ __forceinline__ u32 cvt2(float a, float b) {
  __hip_bfloat162 hh = __float22bfloat162_rn(float2{a, b});
  union { __hip_bfloat162 h; u32 u; } c; c.h = hh; return c.u;
}
__device__ __forceinline__ u16 f2b(float f) {
  __hip_bfloat16 b = __float2bfloat16(f);
  union { __hip_bfloat16 b; u16 u; } c; c.b = b; return c.u;
}
// async global->LDS, 16B per lane. LDS dest = wave-uniform base + lane*16.
__device__ __forceinline__ void glp16(const void* g, void* l) {
  __builtin_amdgcn_global_load_lds(
      (const __attribute__((address_space(1))) u32*)g,
      (__attribute__((address_space(3))) u32*)l, 16, 0, 0);
}

// ---------------- x fp32 -> bf16 ----------------
__global__ __launch_bounds__(256) void k_cvt_x(const float* __restrict__ x,
                                               u16* __restrict__ xb) {
  const size_t i = ((size_t)blockIdx.x * 256 + threadIdx.x) * 8;
  float4 v0 = *(const float4*)(x + i);
  float4 v1 = *(const float4*)(x + i + 4);
  uint4 o;
  o.x = cvt2(v0.x, v0.y); o.y = cvt2(v0.z, v0.w);
  o.z = cvt2(v1.x, v1.y); o.w = cvt2(v1.z, v1.w);
  *(uint4*)(xb + i) = o;
}

// ---------------- router: fp32 logits, top-8, renorm, dispatch ----------------
__global__ __launch_bounds__(256) void k_router(
    const float* __restrict__ x, const float* __restrict__ rw,
    int* __restrict__ counts, int* __restrict__ slot_token,
    float* __restrict__ slot_w)
{
  const int lane = threadIdx.x & 63;
  const int tok  = blockIdx.x * 4 + (threadIdx.x >> 6);
  const float* xr = x + (size_t)tok * D_DIM;

  float acc = 0.f;
  for (int d0 = 0; d0 < D_DIM; d0 += 64) {
    float xv = xr[d0 + lane];
    #pragma unroll
    for (int j = 0; j < 64; ++j) {
      float xj = __shfl(xv, j, 64);
      acc = fmaf(xj, rw[(size_t)(d0 + j) * NE + lane], acc);
    }
  }

  float v = acc; int vi = lane;
  float wk[8]; int ei[8];
  float mx0 = 0.f, wsum = 0.f;
  #pragma unroll
  for (int k = 0; k < 8; ++k) {
    float mv = v; int mi = vi;
    #pragma unroll
    for (int off = 32; off >= 1; off >>= 1) {
      float ov = __shfl_xor(mv, off, 64);
      int   oi = __shfl_xor(mi, off, 64);
      if (ov > mv || (ov == mv && oi < mi)) { mv = ov; mi = oi; }
    }
    if (k == 0) mx0 = mv;
    float ew = __expf(mv - mx0);
    wk[k] = ew; ei[k] = mi; wsum += ew;
    if (lane == mi) v = -3.4e38f;
  }

  if (lane == 0) {
    float inv = 1.f / wsum;
    #pragma unroll
    for (int k = 0; k < 8; ++k) {
      int ee   = ei[k];
      int slot = atomicAdd(&counts[ee], 1);
      if (slot < CAP) {
        slot_token[ee * CAP + slot] = tok;
        slot_w[ee * CAP + slot]     = wk[k] * inv;
      }
    }
  }
}

// ---------------- gate/up fused GEMM + SwiGLU -> h (bf16) ----------------
// 1-D grid 6144, XCD-swizzled. Tile 128m x 64n, BK=64, 2-phase pipeline.
__global__ __launch_bounds__(256) void k_mlp1(
    const u16* __restrict__ xb, const float* __restrict__ gate,
    const float* __restrict__ up, const int* __restrict__ counts,
    const int* __restrict__ slot_token, u16* __restrict__ h)
{
  // decode: xcd = i&7 hosts (e,nt) pairs with (e*12+nt)%8 == xcd; mt fastest.
  const int i   = blockIdx.x;
  const int xcd = i & 7;
  const int p   = i >> 3;          // 0..767
  const int mt  = p & 7;
  const int pe  = p >> 3;          // 0..95
  const int val = pe * 8 + xcd;    // 0..767 == e*12 + nt
  const int e   = val / 12;
  const int nt  = val % 12;

  int cnt = counts[e]; if (cnt > CAP) cnt = CAP;
  const int m0 = mt * 128;
  if (m0 >= cnt) return;
  const int n0 = nt * 64;

  const int t = threadIdx.x;
  const int lane = t & 63, wv = t >> 6;
  const int li = lane & 15, gq = lane >> 4;
  const int wr = wv >> 1, wc = wv & 1;

  __shared__ u16 As[2][8 * 128 * 8];   // 32 KB
  __shared__ u16 Bg[2][8 * 64 * 8];    // 16 KB
  __shared__ u16 Bu[2][8 * 64 * 8];    // 16 KB

  const int mh  = wv & 1;
  const int kgA = (wv >> 1) * 4;
  const int tok = slot_token[e * CAP + m0 + mh * 64 + lane];  // dead slots -> 0
  const u16* xrow = xb + (size_t)tok * D_DIM;

  const float* gb = gate + (size_t)e * D_DIM * I_DIM + n0 + lane;
  const float* ub = up   + (size_t)e * D_DIM * I_DIM + n0 + lane;

  f32x4 ag[4][2], au[4][2];
  #pragma unroll
  for (int m = 0; m < 4; ++m)
    #pragma unroll
    for (int n = 0; n < 2; ++n) {
      f32x4 z = {0.f, 0.f, 0.f, 0.f};
      ag[m][n] = z; au[m][n] = z;
    }

  float gv[2][8], uv[2][8];

  // ---- prologue: prefetch tile 0 ----
  #pragma unroll
  for (int q = 0; q < 4; ++q) {
    const int kg = kgA + q;
    glp16(xrow + kg * 8, &As[0][(kg * 128 + mh * 64) * 8]);
  }
  #pragma unroll
  for (int c = 0; c < 2; ++c) {
    const int kg = wv * 2 + c;
    #pragma unroll
    for (int j = 0; j < 8; ++j) {
      gv[c][j] = gb[(size_t)(kg * 8 + j) * I_DIM];
      uv[c][j] = ub[(size_t)(kg * 8 + j) * I_DIM];
    }
  }

  int buf = 0;
  for (int kk = 0; kk < D_DIM; kk += 64) {
    // write B(t) regs -> LDS[buf]
    #pragma unroll
    for (int c = 0; c < 2; ++c) {
      const int kg = wv * 2 + c;
      uint4 og, ou;
      og.x = cvt2(gv[c][0], gv[c][1]); og.y = cvt2(gv[c][2], gv[c][3]);
      og.z = cvt2(gv[c][4], gv[c][5]); og.w = cvt2(gv[c][6], gv[c][7]);
      ou.x = cvt2(uv[c][0], uv[c][1]); ou.y = cvt2(uv[c][2], uv[c][3]);
      ou.z = cvt2(uv[c][4], uv[c][5]); ou.w = cvt2(uv[c][6], uv[c][7]);
      *(uint4*)&Bg[buf][(kg * 64 + lane) * 8] = og;
      *(uint4*)&Bu[buf][(kg * 64 + lane) * 8] = ou;
    }
    __syncthreads();   // A(t) glp drained (implicit vmcnt0), B writes visible

    // prefetch tile t+1 into buf^1 / regs
    if (kk + 64 < D_DIM) {
      #pragma unroll
      for (int q = 0; q < 4; ++q) {
        const int kg = kgA + q;
        glp16(xrow + kk + 64 + kg * 8, &As[buf ^ 1][(kg * 128 + mh * 64) * 8]);
      }
      #pragma unroll
      for (int c = 0; c < 2; ++c) {
        const int kg = wv * 2 + c;
        #pragma unroll
        for (int j = 0; j < 8; ++j) {
          gv[c][j] = gb[(size_t)(kk + 64 + kg * 8 + j) * I_DIM];
          uv[c][j] = ub[(size_t)(kk + 64 + kg * 8 + j) * I_DIM];
        }
      }
    }

    // MFMA on LDS[buf]
    #pragma unroll
    for (int kc = 0; kc < 2; ++kc) {
      const int kg = kc * 4 + gq;
      bf16x8 a0 = *(const bf16x8*)&As[buf][(kg * 128 + wr * 64 +      li) * 8];
      bf16x8 a1 = *(const bf16x8*)&As[buf][(kg * 128 + wr * 64 + 16 + li) * 8];
      bf16x8 a2 = *(const bf16x8*)&As[buf][(kg * 128 + wr * 64 + 32 + li) * 8];
      bf16x8 a3 = *(const bf16x8*)&As[buf][(kg * 128 + wr * 64 + 48 + li) * 8];
      bf16x8 g0 = *(const bf16x8*)&Bg[buf][(kg * 64 + wc * 32 +      li) * 8];
      bf16x8 g1 = *(const bf16x8*)&Bg[buf][(kg * 64 + wc * 32 + 16 + li) * 8];
      bf16x8 u0 = *(const bf16x8*)&Bu[buf][(kg * 64 + wc * 32 +      li) * 8];
      bf16x8 u1 = *(const bf16x8*)&Bu[buf][(kg * 64 + wc * 32 + 16 + li) * 8];
      ag[0][0] = __builtin_amdgcn_mfma_f32_16x16x32_bf16(a0, g0, ag[0][0], 0, 0, 0);
      ag[1][0] = __builtin_amdgcn_mfma_f32_16x16x32_bf16(a1, g0, ag[1][0], 0, 0, 0);
      ag[2][0] = __builtin_amdgcn_mfma_f32_16x16x32_bf16(a2, g0, ag[2][0], 0, 0, 0);
      ag[3][0] = __builtin_amdgcn_mfma_f32_16x16x32_bf16(a3, g0, ag[3][0], 0, 0, 0);
      ag[0][1] = __builtin_amdgcn_mfma_f32_16x16x32_bf16(a0, g1, ag[0][1], 0, 0, 0);
      ag[1][1] = __builtin_amdgcn_mfma_f32_16x16x32_bf16(a1, g1, ag[1][1], 0, 0, 0);
      ag[2][1] = __builtin_amdgcn_mfma_f32_16x16x32_bf16(a2, g1, ag[2][1], 0, 0, 0);
      ag[3][1] = __builtin_amdgcn_mfma_f32_16x16x32_bf16(a3, g1, ag[3][1], 0, 0, 0);
      au[0][0] = __builtin_amdgcn_mfma_f32_16x16x32_bf16(a0, u0, au[0][0], 0, 0, 0);
      au[1][0] = __builtin_amdgcn_mfma_f32_16x16x32_bf16(a1, u0, au[1][0], 0, 0, 0);
      au[2][0] = __builtin_amdgcn_mfma_f32_16x16x32_bf16(a2, u0, au[2][0], 0, 0, 0);
      au[3][0] = __builtin_amdgcn_mfma_f32_16x16x32_bf16(a3, u0, au[3][0], 0, 0, 0);
      au[0][1] = __builtin_amdgcn_mfma_f32_16x16x32_bf16(a0, u1, au[0][1], 0, 0, 0);
      au[1][1] = __builtin_amdgcn_mfma_f32_16x16x32_bf16(a1, u1, au[1][1], 0, 0, 0);
      au[2][1] = __builtin_amdgcn_mfma_f32_16x16x32_bf16(a2, u1, au[2][1], 0, 0, 0);
      au[3][1] = __builtin_amdgcn_mfma_f32_16x16x32_bf16(a3, u1, au[3][1], 0, 0, 0);
    }
    __syncthreads();   // protects next iter's writes; drains prefetch (flew under MFMA)
    buf ^= 1;
  }

  // epilogue: h = silu(g) * u, bf16. Write all 128 rows (dead rows harmless).
  #pragma unroll
  for (int mf = 0; mf < 4; ++mf) {
    #pragma unroll
    for (int j = 0; j < 4; ++j) {
      const int slot = m0 + wr * 64 + mf * 16 + gq * 4 + j;
      u16* hr = h + (size_t)(e * CAP + slot) * I_DIM + n0 + wc * 32 + li;
      #pragma unroll
      for (int nf = 0; nf < 2; ++nf) {
        float gg = ag[mf][nf][j];
        float uu = au[mf][nf][j];
        hr[nf * 16] = f2b(gg * uu / (1.f + __expf(-gg)));
      }
    }
  }
}

// ---------------- down GEMM + weighted scatter-add ----------------
// 1-D grid 8192, XCD-swizzled. Tile 128m x 128n, BK=64, 2-phase pipeline.
__global__ __launch_bounds__(256) void k_mlp2(
    const u16* __restrict__ h, const float* __restrict__ down,
    const int* __restrict__ counts, const int* __restrict__ slot_token,
    const float* __restrict__ slot_w, float* __restrict__ out)
{
  const int i   = blockIdx.x;
  const int xcd = i & 7;
  const int p   = i >> 3;          // 0..1023
  const int mt  = p & 7;
  const int pe  = p >> 3;          // 0..127
  const int val = pe * 8 + xcd;    // 0..1023 == e*16 + nt
  const int e   = val >> 4;
  const int nt  = val & 15;

  int cnt = counts[e]; if (cnt > CAP) cnt = CAP;
  const int m0 = mt * 128;
  if (m0 >= cnt) return;
  const int n0 = nt * 128;

  const int t = threadIdx.x;
  const int lane = t & 63, wv = t >> 6;
  const int li = lane & 15, gq = lane >> 4;
  const int wm = (wv >> 1) * 64, wn = (wv & 1) * 64;

  __shared__ u16 As[2][8 * 128 * 8];   // 32 KB
  __shared__ u16 Bt[2][8 * 128 * 8];   // 32 KB

  const int mh  = wv & 1;
  const int kgA = (wv >> 1) * 4;
  const u16* hrow = h + (size_t)(e * CAP + m0 + mh * 64 + lane) * I_DIM;

  const int nh  = wv >> 1;
  const int kgB = (wv & 1) * 4;
  const float* db = down + (size_t)e * I_DIM * D_DIM + n0 + nh * 64 + lane;

  f32x4 acc[4][4];
  #pragma unroll
  for (int m = 0; m < 4; ++m)
    #pragma unroll
    for (int n = 0; n < 4; ++n) { f32x4 z = {0.f,0.f,0.f,0.f}; acc[m][n] = z; }

  float dv[4][8];

  // ---- prologue: prefetch tile 0 ----
  #pragma unroll
  for (int q = 0; q < 4; ++q) {
    const int kg = kgA + q;
    glp16(hrow + kg * 8, &As[0][(kg * 128 + mh * 64) * 8]);
  }
  #pragma unroll
  for (int c = 0; c < 4; ++c) {
    const int kg = kgB + c;
    #pragma unroll
    for (int j = 0; j < 8; ++j)
      dv[c][j] = db[(size_t)(kg * 8 + j) * D_DIM];
  }

  int buf = 0;
  for (int kk = 0; kk < I_DIM; kk += 64) {
    #pragma unroll
    for (int c = 0; c < 4; ++c) {
      const int kg = kgB + c;
      uint4 o;
      o.x = cvt2(dv[c][0], dv[c][1]); o.y = cvt2(dv[c][2], dv[c][3]);
      o.z = cvt2(dv[c][4], dv[c][5]); o.w = cvt2(dv[c][6], dv[c][7]);
      *(uint4*)&Bt[buf][(kg * 128 + nh * 64 + lane) * 8] = o;
    }
    __syncthreads();

    if (kk + 64 < I_DIM) {
      #pragma unroll
      for (int q = 0; q < 4; ++q) {
        const int kg = kgA + q;
        glp16(hrow + kk + 64 + kg * 8, &As[buf ^ 1][(kg * 128 + mh * 64) * 8]);
      }
      #pragma unroll
      for (int c = 0; c < 4; ++c) {
        const int kg = kgB + c;
        #pragma unroll
        for (int j = 0; j < 8; ++j)
          dv[c][j] = db[(size_t)(kk + 64 + kg * 8 + j) * D_DIM];
      }
    }

    #pragma unroll
    for (int kc = 0; kc < 2; ++kc) {
      const int kg = kc * 4 + gq;
      bf16x8 a[4], b[4];
      #pragma unroll
      for (int mf = 0; mf < 4; ++mf)
        a[mf] = *(const bf16x8*)&As[buf][(kg * 128 + wm + mf * 16 + li) * 8];
      #pragma unroll
      for (int nf = 0; nf < 4; ++nf)
        b[nf] = *(const bf16x8*)&Bt[buf][(kg * 128 + wn + nf * 16 + li) * 8];
      #pragma unroll
      for (int mf = 0; mf < 4; ++mf)
        #pragma unroll
        for (int nf = 0; nf < 4; ++nf)
          acc[mf][nf] = __builtin_amdgcn_mfma_f32_16x16x32_bf16(a[mf], b[nf], acc[mf][nf], 0, 0, 0);
    }
    __syncthreads();
    buf ^= 1;
  }

  #pragma unroll
  for (int mf = 0; mf < 4; ++mf) {
    #pragma unroll
    for (int j = 0; j < 4; ++j) {
      const int slot = m0 + wm + mf * 16 + gq * 4 + j;
      if (slot < cnt) {
        const int   tk  = slot_token[e * CAP + slot];
        const float wgt = slot_w[e * CAP + slot];
        float* orow = out + (size_t)tk * D_DIM + n0 + wn + li;
        #pragma unroll
        for (int nf = 0; nf < 4; ++nf)
          atomicAdd(&orow[nf * 16], wgt * acc[mf][nf][j]);
      }
    }
  }
}

extern "C" void kernel_launch(void* const* d_in, const int* in_sizes, int n_in,
                              void* d_out, int out_size, void* d_ws, size_t ws_size,
                              hipStream_t stream) {
  const float* x    = (const float*)d_in[0];
  const float* rw   = (const float*)d_in[1];
  const float* gate = (const float*)d_in[2];
  const float* up   = (const float*)d_in[3];
  const float* down = (const float*)d_in[4];
  float* out = (float*)d_out;

  char* ws = (char*)d_ws;
  int*   counts     = (int*)ws;                                    // 256 B (pad 1 KB)
  int*   slot_token = (int*)(ws + 1024);                           // 256 KB
  float* slot_w     = (float*)(ws + 1024 + (size_t)NE * CAP * 4);  // 256 KB
  u16*   xb         = (u16*)(ws + 1024 + (size_t)NE * CAP * 8);    // 16.78 MB
  u16*   h          = (u16*)(ws + 1024 + (size_t)NE * CAP * 8
                                  + (size_t)NTOK * D_DIM * 2);     // 100.7 MB

  hipMemsetAsync(counts, 0, NE * sizeof(int), stream);
  hipMemsetAsync(slot_token, 0, (size_t)NE * CAP * sizeof(int), stream);
  hipMemsetAsync(out, 0, (size_t)out_size * sizeof(float), stream);

  k_cvt_x <<<dim3((NTOK * D_DIM) / (256 * 8)), 256, 0, stream>>>(x, xb);
  k_router<<<dim3(NTOK / 4),                   256, 0, stream>>>(x, rw, counts, slot_token, slot_w);
  k_mlp1  <<<dim3(6144),                       256, 0, stream>>>(xb, gate, up, counts, slot_token, h);
  k_mlp2  <<<dim3(8192),                       256, 0, stream>>>(h, down, counts, slot_token, slot_w, out);
}

// Round 4
// 1372.953 us; speedup vs baseline: 1.3728x; 1.0384x over previous
//
#include <hip/hip_runtime.h>
#include <hip/hip_bf16.h>

typedef __attribute__((ext_vector_type(4))) float f32x4;
typedef __attribute__((ext_vector_type(8))) short bf16x8;
typedef unsigned int   u32;
typedef unsigned short u16;

#define D_DIM 2048
#define I_DIM 768
#define NE    64
#define CAP   1024
#define NTOK  4096

__device__ __forceinline__ u32 cvt2(float a, float b) {
  __hip_bfloat162 hh = __float22bfloat162_rn(float2{a, b});
  union { __hip_bfloat162 h; u32 u; } c; c.h = hh; return c.u;
}
__device__ __forceinline__ u16 f2b(float f) {
  __hip_bfloat16 b = __float2bfloat16(f);
  union { __hip_bfloat16 b; u16 u; } c; c.b = b; return c.u;
}
// async global->LDS, 16B per lane. LDS dest = wave-uniform base + lane*16.
__device__ __forceinline__ void glp16(const void* g, void* l) {
  __builtin_amdgcn_global_load_lds(
      (const __attribute__((address_space(1))) u32*)g,
      (__attribute__((address_space(3))) u32*)l, 16, 0, 0);
}

// ---------------- x fp32 -> bf16 ----------------
__global__ __launch_bounds__(256) void k_cvt_x(const float* __restrict__ x,
                                               u16* __restrict__ xb) {
  const size_t i = ((size_t)blockIdx.x * 256 + threadIdx.x) * 8;
  float4 v0 = *(const float4*)(x + i);
  float4 v1 = *(const float4*)(x + i + 4);
  uint4 o;
  o.x = cvt2(v0.x, v0.y); o.y = cvt2(v0.z, v0.w);
  o.z = cvt2(v1.x, v1.y); o.w = cvt2(v1.z, v1.w);
  *(uint4*)(xb + i) = o;
}

// ---------------- router: fp32 logits, top-8, renorm, dispatch ----------------
__global__ __launch_bounds__(256) void k_router(
    const float* __restrict__ x, const float* __restrict__ rw,
    int* __restrict__ counts, int* __restrict__ slot_token,
    float* __restrict__ slot_w)
{
  const int lane = threadIdx.x & 63;
  const int tok  = blockIdx.x * 4 + (threadIdx.x >> 6);
  const float* xr = x + (size_t)tok * D_DIM;

  float acc = 0.f;
  for (int d0 = 0; d0 < D_DIM; d0 += 64) {
    float xv = xr[d0 + lane];
    #pragma unroll
    for (int j = 0; j < 64; ++j) {
      float xj = __shfl(xv, j, 64);
      acc = fmaf(xj, rw[(size_t)(d0 + j) * NE + lane], acc);
    }
  }

  float v = acc; int vi = lane;
  float wk[8]; int ei[8];
  float mx0 = 0.f, wsum = 0.f;
  #pragma unroll
  for (int k = 0; k < 8; ++k) {
    float mv = v; int mi = vi;
    #pragma unroll
    for (int off = 32; off >= 1; off >>= 1) {
      float ov = __shfl_xor(mv, off, 64);
      int   oi = __shfl_xor(mi, off, 64);
      if (ov > mv || (ov == mv && oi < mi)) { mv = ov; mi = oi; }
    }
    if (k == 0) mx0 = mv;
    float ew = __expf(mv - mx0);
    wk[k] = ew; ei[k] = mi; wsum += ew;
    if (lane == mi) v = -3.4e38f;
  }

  if (lane == 0) {
    float inv = 1.f / wsum;
    #pragma unroll
    for (int k = 0; k < 8; ++k) {
      int ee   = ei[k];
      int slot = atomicAdd(&counts[ee], 1);
      if (slot < CAP) {
        slot_token[ee * CAP + slot] = tok;
        slot_w[ee * CAP + slot]     = wk[k] * inv;
      }
    }
  }
}

// ---------------- gate/up fused GEMM + SwiGLU -> h (bf16) ----------------
// 1-D grid 6144, XCD-swizzled. Tile 128m x 64n, BK=32, single-barrier pipeline.
__global__ __launch_bounds__(256, 4) void k_mlp1(
    const u16* __restrict__ xb, const float* __restrict__ gate,
    const float* __restrict__ up, const int* __restrict__ counts,
    const int* __restrict__ slot_token, u16* __restrict__ h)
{
  // decode: xcd = i&7 hosts (e,nt) pairs with (e*12+nt)%8 == xcd; mt fastest.
  const int i   = blockIdx.x;
  const int xcd = i & 7;
  const int p   = i >> 3;          // 0..767
  const int mt  = p & 7;
  const int pe  = p >> 3;          // 0..95
  const int val = pe * 8 + xcd;    // 0..767 == e*12 + nt
  const int e   = val / 12;
  const int nt  = val % 12;

  int cnt = counts[e]; if (cnt > CAP) cnt = CAP;
  const int m0 = mt * 128;
  if (m0 >= cnt) return;
  const int n0 = nt * 64;

  const int t = threadIdx.x;
  const int lane = t & 63, wv = t >> 6;
  const int li = lane & 15, gq = lane >> 4;
  const int wr = wv >> 1, wc = wv & 1;

  __shared__ u16 As[2][4 * 128 * 8];   // [kg(4)][m(128)][8]  16 KB
  __shared__ u16 Bg[2][4 * 64 * 8];    //  8 KB
  __shared__ u16 Bu[2][4 * 64 * 8];    //  8 KB

  // A staging: wave wv -> m-half mh, kg pair {kgA, kgA+1}
  const int mh  = wv & 1;
  const int kgA = (wv >> 1) * 2;
  const int tok = slot_token[e * CAP + m0 + mh * 64 + lane];  // dead slots -> 0
  const u16* xrow = xb + (size_t)tok * D_DIM;

  // B staging: wave wv owns cells (kg=wv, n=lane) for both gate and up
  const float* gb = gate + (size_t)e * D_DIM * I_DIM + n0 + lane;
  const float* ub = up   + (size_t)e * D_DIM * I_DIM + n0 + lane;

  f32x4 ag[4][2], au[4][2];
  #pragma unroll
  for (int m = 0; m < 4; ++m)
    #pragma unroll
    for (int n = 0; n < 2; ++n) {
      f32x4 z = {0.f, 0.f, 0.f, 0.f};
      ag[m][n] = z; au[m][n] = z;
    }

  float gv[8], uv[8];

  // ---- prologue: stage tile 0 into buf 0 ----
  glp16(xrow + (kgA    ) * 8, &As[0][((kgA    ) * 128 + mh * 64) * 8]);
  glp16(xrow + (kgA + 1) * 8, &As[0][((kgA + 1) * 128 + mh * 64) * 8]);
  #pragma unroll
  for (int j = 0; j < 8; ++j) {
    gv[j] = gb[(size_t)(wv * 8 + j) * I_DIM];
    uv[j] = ub[(size_t)(wv * 8 + j) * I_DIM];
  }
  {
    uint4 og, ou;
    og.x = cvt2(gv[0], gv[1]); og.y = cvt2(gv[2], gv[3]);
    og.z = cvt2(gv[4], gv[5]); og.w = cvt2(gv[6], gv[7]);
    ou.x = cvt2(uv[0], uv[1]); ou.y = cvt2(uv[2], uv[3]);
    ou.z = cvt2(uv[4], uv[5]); ou.w = cvt2(uv[6], uv[7]);
    *(uint4*)&Bg[0][(wv * 64 + lane) * 8] = og;
    *(uint4*)&Bu[0][(wv * 64 + lane) * 8] = ou;
  }
  __syncthreads();   // tile 0 fully staged (glp drained by barrier's vmcnt0)

  int buf = 0;
  for (int kk = 0; kk < D_DIM; kk += 32) {
    const bool more = (kk + 32) < D_DIM;
    // issue prefetch of tile t+1 (flies during MFMA below)
    if (more) {
      glp16(xrow + kk + 32 + (kgA    ) * 8, &As[buf ^ 1][((kgA    ) * 128 + mh * 64) * 8]);
      glp16(xrow + kk + 32 + (kgA + 1) * 8, &As[buf ^ 1][((kgA + 1) * 128 + mh * 64) * 8]);
      #pragma unroll
      for (int j = 0; j < 8; ++j) {
        gv[j] = gb[(size_t)(kk + 32 + wv * 8 + j) * I_DIM];
        uv[j] = ub[(size_t)(kk + 32 + wv * 8 + j) * I_DIM];
      }
    }

    // MFMA on buf (kg = gq)
    {
      bf16x8 a0 = *(const bf16x8*)&As[buf][(gq * 128 + wr * 64 +      li) * 8];
      bf16x8 a1 = *(const bf16x8*)&As[buf][(gq * 128 + wr * 64 + 16 + li) * 8];
      bf16x8 a2 = *(const bf16x8*)&As[buf][(gq * 128 + wr * 64 + 32 + li) * 8];
      bf16x8 a3 = *(const bf16x8*)&As[buf][(gq * 128 + wr * 64 + 48 + li) * 8];
      bf16x8 g0 = *(const bf16x8*)&Bg[buf][(gq * 64 + wc * 32 +      li) * 8];
      bf16x8 g1 = *(const bf16x8*)&Bg[buf][(gq * 64 + wc * 32 + 16 + li) * 8];
      bf16x8 u0 = *(const bf16x8*)&Bu[buf][(gq * 64 + wc * 32 +      li) * 8];
      bf16x8 u1 = *(const bf16x8*)&Bu[buf][(gq * 64 + wc * 32 + 16 + li) * 8];
      ag[0][0] = __builtin_amdgcn_mfma_f32_16x16x32_bf16(a0, g0, ag[0][0], 0, 0, 0);
      ag[1][0] = __builtin_amdgcn_mfma_f32_16x16x32_bf16(a1, g0, ag[1][0], 0, 0, 0);
      ag[2][0] = __builtin_amdgcn_mfma_f32_16x16x32_bf16(a2, g0, ag[2][0], 0, 0, 0);
      ag[3][0] = __builtin_amdgcn_mfma_f32_16x16x32_bf16(a3, g0, ag[3][0], 0, 0, 0);
      ag[0][1] = __builtin_amdgcn_mfma_f32_16x16x32_bf16(a0, g1, ag[0][1], 0, 0, 0);
      ag[1][1] = __builtin_amdgcn_mfma_f32_16x16x32_bf16(a1, g1, ag[1][1], 0, 0, 0);
      ag[2][1] = __builtin_amdgcn_mfma_f32_16x16x32_bf16(a2, g1, ag[2][1], 0, 0, 0);
      ag[3][1] = __builtin_amdgcn_mfma_f32_16x16x32_bf16(a3, g1, ag[3][1], 0, 0, 0);
      au[0][0] = __builtin_amdgcn_mfma_f32_16x16x32_bf16(a0, u0, au[0][0], 0, 0, 0);
      au[1][0] = __builtin_amdgcn_mfma_f32_16x16x32_bf16(a1, u0, au[1][0], 0, 0, 0);
      au[2][0] = __builtin_amdgcn_mfma_f32_16x16x32_bf16(a2, u0, au[2][0], 0, 0, 0);
      au[3][0] = __builtin_amdgcn_mfma_f32_16x16x32_bf16(a3, u0, au[3][0], 0, 0, 0);
      au[0][1] = __builtin_amdgcn_mfma_f32_16x16x32_bf16(a0, u1, au[0][1], 0, 0, 0);
      au[1][1] = __builtin_amdgcn_mfma_f32_16x16x32_bf16(a1, u1, au[1][1], 0, 0, 0);
      au[2][1] = __builtin_amdgcn_mfma_f32_16x16x32_bf16(a2, u1, au[2][1], 0, 0, 0);
      au[3][1] = __builtin_amdgcn_mfma_f32_16x16x32_bf16(a3, u1, au[3][1], 0, 0, 0);
    }

    // convert + write B(t+1) into buf^1 (after MFMA so loads flew under it)
    if (more) {
      uint4 og, ou;
      og.x = cvt2(gv[0], gv[1]); og.y = cvt2(gv[2], gv[3]);
      og.z = cvt2(gv[4], gv[5]); og.w = cvt2(gv[6], gv[7]);
      ou.x = cvt2(uv[0], uv[1]); ou.y = cvt2(uv[2], uv[3]);
      ou.z = cvt2(uv[4], uv[5]); ou.w = cvt2(uv[6], uv[7]);
      *(uint4*)&Bg[buf ^ 1][(wv * 64 + lane) * 8] = og;
      *(uint4*)&Bu[buf ^ 1][(wv * 64 + lane) * 8] = ou;
    }
    __syncthreads();   // single barrier: reads(t) done, writes(t+1) drained/visible
    buf ^= 1;
  }

  // epilogue: h = silu(g) * u, bf16. Write all 128 rows (dead rows harmless).
  #pragma unroll
  for (int mf = 0; mf < 4; ++mf) {
    #pragma unroll
    for (int j = 0; j < 4; ++j) {
      const int slot = m0 + wr * 64 + mf * 16 + gq * 4 + j;
      u16* hr = h + (size_t)(e * CAP + slot) * I_DIM + n0 + wc * 32 + li;
      #pragma unroll
      for (int nf = 0; nf < 2; ++nf) {
        float gg = ag[mf][nf][j];
        float uu = au[mf][nf][j];
        hr[nf * 16] = f2b(gg * uu / (1.f + __expf(-gg)));
      }
    }
  }
}

// ---------------- down GEMM + weighted scatter-add ----------------
// 1-D grid 8192, XCD-swizzled. Tile 128m x 128n, BK=32, single-barrier pipeline.
__global__ __launch_bounds__(256, 4) void k_mlp2(
    const u16* __restrict__ h, const float* __restrict__ down,
    const int* __restrict__ counts, const int* __restrict__ slot_token,
    const float* __restrict__ slot_w, float* __restrict__ out)
{
  const int i   = blockIdx.x;
  const int xcd = i & 7;
  const int p   = i >> 3;          // 0..1023
  const int mt  = p & 7;
  const int pe  = p >> 3;          // 0..127
  const int val = pe * 8 + xcd;    // 0..1023 == e*16 + nt
  const int e   = val >> 4;
  const int nt  = val & 15;

  int cnt = counts[e]; if (cnt > CAP) cnt = CAP;
  const int m0 = mt * 128;
  if (m0 >= cnt) return;
  const int n0 = nt * 128;

  const int t = threadIdx.x;
  const int lane = t & 63, wv = t >> 6;
  const int li = lane & 15, gq = lane >> 4;
  const int wm = (wv >> 1) * 64, wn = (wv & 1) * 64;

  __shared__ u16 As[2][4 * 128 * 8];   // [kg][m][8]  16 KB
  __shared__ u16 Bt[2][4 * 128 * 8];   // [kg][n][8]  16 KB

  // A staging: wave wv -> m-half mh, kg pair {kgA, kgA+1}
  const int mh  = wv & 1;
  const int kgA = (wv >> 1) * 2;
  const u16* hrow = h + (size_t)(e * CAP + m0 + mh * 64 + lane) * I_DIM;

  // B staging: thread owns cells (kg = kgB + c, n = nB), c = 0,1
  const int nB  = t & 127;
  const int kgB = (t >> 7) * 2;
  const float* db = down + (size_t)e * I_DIM * D_DIM + n0 + nB;

  f32x4 acc[4][4];
  #pragma unroll
  for (int m = 0; m < 4; ++m)
    #pragma unroll
    for (int n = 0; n < 4; ++n) { f32x4 z = {0.f,0.f,0.f,0.f}; acc[m][n] = z; }

  float dv[2][8];

  // ---- prologue: stage tile 0 into buf 0 ----
  glp16(hrow + (kgA    ) * 8, &As[0][((kgA    ) * 128 + mh * 64) * 8]);
  glp16(hrow + (kgA + 1) * 8, &As[0][((kgA + 1) * 128 + mh * 64) * 8]);
  #pragma unroll
  for (int c = 0; c < 2; ++c)
    #pragma unroll
    for (int j = 0; j < 8; ++j)
      dv[c][j] = db[(size_t)((kgB + c) * 8 + j) * D_DIM];
  #pragma unroll
  for (int c = 0; c < 2; ++c) {
    uint4 o;
    o.x = cvt2(dv[c][0], dv[c][1]); o.y = cvt2(dv[c][2], dv[c][3]);
    o.z = cvt2(dv[c][4], dv[c][5]); o.w = cvt2(dv[c][6], dv[c][7]);
    *(uint4*)&Bt[0][((kgB + c) * 128 + nB) * 8] = o;
  }
  __syncthreads();

  int buf = 0;
  for (int kk = 0; kk < I_DIM; kk += 32) {
    const bool more = (kk + 32) < I_DIM;
    if (more) {
      glp16(hrow + kk + 32 + (kgA    ) * 8, &As[buf ^ 1][((kgA    ) * 128 + mh * 64) * 8]);
      glp16(hrow + kk + 32 + (kgA + 1) * 8, &As[buf ^ 1][((kgA + 1) * 128 + mh * 64) * 8]);
      #pragma unroll
      for (int c = 0; c < 2; ++c)
        #pragma unroll
        for (int j = 0; j < 8; ++j)
          dv[c][j] = db[(size_t)(kk + 32 + (kgB + c) * 8 + j) * D_DIM];
    }

    {
      bf16x8 a[4], b[4];
      #pragma unroll
      for (int mf = 0; mf < 4; ++mf)
        a[mf] = *(const bf16x8*)&As[buf][(gq * 128 + wm + mf * 16 + li) * 8];
      #pragma unroll
      for (int nf = 0; nf < 4; ++nf)
        b[nf] = *(const bf16x8*)&Bt[buf][(gq * 128 + wn + nf * 16 + li) * 8];
      #pragma unroll
      for (int mf = 0; mf < 4; ++mf)
        #pragma unroll
        for (int nf = 0; nf < 4; ++nf)
          acc[mf][nf] = __builtin_amdgcn_mfma_f32_16x16x32_bf16(a[mf], b[nf], acc[mf][nf], 0, 0, 0);
    }

    if (more) {
      #pragma unroll
      for (int c = 0; c < 2; ++c) {
        uint4 o;
        o.x = cvt2(dv[c][0], dv[c][1]); o.y = cvt2(dv[c][2], dv[c][3]);
        o.z = cvt2(dv[c][4], dv[c][5]); o.w = cvt2(dv[c][6], dv[c][7]);
        *(uint4*)&Bt[buf ^ 1][((kgB + c) * 128 + nB) * 8] = o;
      }
    }
    __syncthreads();
    buf ^= 1;
  }

  // epilogue: out[tok][d] += w * y   (device-scope fp32 atomics)
  #pragma unroll
  for (int mf = 0; mf < 4; ++mf) {
    #pragma unroll
    for (int j = 0; j < 4; ++j) {
      const int slot = m0 + wm + mf * 16 + gq * 4 + j;
      if (slot < cnt) {
        const int   tk  = slot_token[e * CAP + slot];
        const float wgt = slot_w[e * CAP + slot];
        float* orow = out + (size_t)tk * D_DIM + n0 + wn + li;
        #pragma unroll
        for (int nf = 0; nf < 4; ++nf)
          atomicAdd(&orow[nf * 16], wgt * acc[mf][nf][j]);
      }
    }
  }
}

extern "C" void kernel_launch(void* const* d_in, const int* in_sizes, int n_in,
                              void* d_out, int out_size, void* d_ws, size_t ws_size,
                              hipStream_t stream) {
  const float* x    = (const float*)d_in[0];
  const float* rw   = (const float*)d_in[1];
  const float* gate = (const float*)d_in[2];
  const float* up   = (const float*)d_in[3];
  const float* down = (const float*)d_in[4];
  float* out = (float*)d_out;

  char* ws = (char*)d_ws;
  int*   counts     = (int*)ws;                                    // 256 B (pad 1 KB)
  int*   slot_token = (int*)(ws + 1024);                           // 256 KB
  float* slot_w     = (float*)(ws + 1024 + (size_t)NE * CAP * 4);  // 256 KB
  u16*   xb         = (u16*)(ws + 1024 + (size_t)NE * CAP * 8);    // 16.78 MB
  u16*   h          = (u16*)(ws + 1024 + (size_t)NE * CAP * 8
                                  + (size_t)NTOK * D_DIM * 2);     // 100.7 MB

  hipMemsetAsync(counts, 0, NE * sizeof(int), stream);
  hipMemsetAsync(slot_token, 0, (size_t)NE * CAP * sizeof(int), stream);
  hipMemsetAsync(out, 0, (size_t)out_size * sizeof(float), stream);

  k_cvt_x <<<dim3((NTOK * D_DIM) / (256 * 8)), 256, 0, stream>>>(x, xb);
  k_router<<<dim3(NTOK / 4),                   256, 0, stream>>>(x, rw, counts, slot_token, slot_w);
  k_mlp1  <<<dim3(6144),                       256, 0, stream>>>(xb, gate, up, counts, slot_token, h);
  k_mlp2  <<<dim3(8192),                       256, 0, stream>>>(h, down, counts, slot_token, slot_w, out);
}